// Round 7
// baseline (337.040 us; speedup 1.0000x reference)
//
#include <hip/hip_runtime.h>
#include <hip/hip_bf16.h>
#include <stdint.h>
#include <math.h>

// Problem constants
#define DD 1024
#define SS 2048
#define BB 4

typedef __bf16 bf16;
typedef __bf16 bf16x8 __attribute__((ext_vector_type(8)));
typedef __bf16 bf16x4 __attribute__((ext_vector_type(4)));
typedef float f32x4 __attribute__((ext_vector_type(4)));

// ---- async global->LDS 16B copy (dest = wave-uniform base + lane*16) ----
__device__ __forceinline__ void gload_lds16(const bf16* g, bf16* l) {
  __builtin_amdgcn_global_load_lds(
      (const __attribute__((address_space(1))) void*)g,
      (__attribute__((address_space(3))) void*)l, 16, 0, 0);
}

// ---- ALL preprocessing in ONE dispatch --------------------------------
// blocks [0,8192):      fp32->bf16 cvt of x -> xb
// blocks [8192,9216):   fp32->bf16 cvt of Wv -> wcat rows [1024,2048)
// blocks [9216,13312):  transpose+cvt R,E,Wq,Wk -> RT,ET,WqT,WkT
// blocks [13312,13344): zero rowsums (8192 floats)
__global__ __launch_bounds__(256) void prep_all(
    const float* __restrict__ x, const float* __restrict__ R,
    const float* __restrict__ E, const float* __restrict__ Wq,
    const float* __restrict__ Wk, const float* __restrict__ Wv,
    bf16* __restrict__ xb, bf16* __restrict__ RT, bf16* __restrict__ ET,
    bf16* __restrict__ WqT, bf16* __restrict__ WkT, bf16* __restrict__ wcat,
    float* __restrict__ rowsums) {
  int bid = blockIdx.x;
  int t = threadIdx.x;
  if (bid < 9216) {
    const float* src;
    bf16* dst;
    int base;
    if (bid < 8192) { src = x; dst = xb; base = bid; }
    else { src = Wv; dst = wcat + 1024 * 1024; base = bid - 8192; }
    int i = (base * 256 + t) * 4;
    float4 v = *(const float4*)(src + i);
    bf16x4 o;
    o.x = (bf16)v.x; o.y = (bf16)v.y; o.z = (bf16)v.z; o.w = (bf16)v.w;
    *(bf16x4*)(dst + i) = o;
  } else if (bid < 13312) {
    int idx = bid - 9216;
    int which = idx >> 10;
    const float* src = (which == 0) ? R : (which == 1) ? E : (which == 2) ? Wq : Wk;
    bf16* dst = (which == 0) ? RT : (which == 1) ? ET : (which == 2) ? WqT : WkT;
    int rem = idx & 1023;
    int bx = rem & 31, by = rem >> 5;
    __shared__ float tile[32][33];
    int tx = t & 31, ty = t >> 5;
    int xcol = bx * 32 + tx;
    int y0 = by * 32;
    for (int r = ty; r < 32; r += 8)
      tile[r][tx] = src[(y0 + r) * DD + xcol];
    __syncthreads();
    int dx = by * 32 + tx;
    int dy0 = bx * 32;
    for (int r = ty; r < 32; r += 8)
      dst[(dy0 + r) * DD + dx] = (bf16)tile[tx][r];
  } else {
    int idx = (bid - 13312) * 256 + t;  // 0..8191
    rowsums[idx] = 0.f;
  }
}

// ---- bf16 GEMM: C = A @ B^T, 128x128x64 tiles, BK=64 (2 sub-tiles) ------
// MODE 0: C bf16 normal (+bias if non-null). Optional GEMV hook: blocks with
//         bx==gemvBx compute gy[by*128+r] = dot(gA[row,:1024], gx) and exit.
// MODE 1: causal scores, fused exp: triangular decode of blockIdx.x;
//         p~ = exp((acc + beta[col])*scale) (0 above diag), bf16 out via
//         swizzled LDS bounce; row sums atomically added to rowsums.
//         `bias` = beta (fp32, indexed bz*SS + n0+col).
// MODE 2: P~ @ V, K truncated at (by+1)*128, by reversed; out fp32 / rowsum.
// MODE 3: C bf16 TRANSPOSED (out[(n0+c)*ldc + m0+r]) via LDS bounce, no bias.
// MODE 4: QKV: bx<8 -> T tile normal bf16 (no bias); bx in [8,16) -> V tile
//         written transposed to vTp[b][d][s] with bias bv; bx==16 -> GEMV.
template <int MODE>
__global__ __launch_bounds__(256, 4)
void gemm_bt(const bf16* __restrict__ Ag, long lda, long sAb,
             const bf16* __restrict__ Bg, long ldb, long sBb,
             void* __restrict__ Cg, long ldc, long sCb,
             const float* __restrict__ bias, float scale, int K,
             bf16* __restrict__ vTp, float* __restrict__ rowsums,
             const bf16* __restrict__ gA, const float* __restrict__ gx,
             float* __restrict__ gy, int gemvBx) {
  __shared__ __align__(16) bf16 smem[16384];  // As | Bs ; reused for bounce
  bf16* As = smem;
  bf16* Bs = smem + 8192;

  int bx = blockIdx.x, by = blockIdx.y, bz = blockIdx.z;
  int t = threadIdx.x;

  if ((MODE == 0 || MODE == 4) && gy && bx == gemvBx) {
    // GEMV: gy[by*128 + r] = gA[row,:] . gx   (1024-dot, 2 threads/row)
    int r = t >> 1, h = t & 1;
    long row = (long)by * 128 + r;
    const bf16* ap = gA + row * 1024 + h * 512;
    const float* xp = gx + h * 512;
    float s = 0.f;
    for (int k = 0; k < 512; k += 8) {
      bf16x8 a8 = *(const bf16x8*)(ap + k);
#pragma unroll
      for (int e = 0; e < 8; e++) s += (float)a8[e] * xp[k + e];
    }
    s += __shfl_xor(s, 1, 64);
    if (h == 0) gy[row] = s;
    return;
  }

  if (MODE == 1) {  // triangular decode: q -> (by, bx<=by)
    int q = bx;
    by = (int)((sqrtf(8.f * q + 1.f) - 1.f) * 0.5f);
    while ((by + 1) * (by + 2) / 2 <= q) by++;
    while (by * (by + 1) / 2 > q) by--;
    bx = q - by * (by + 1) / 2;
  }
  if (MODE == 2) by = 15 - by;  // longest K strips dispatch first
  long m0 = (long)by * 128, n0 = (long)bx * 128;
  const bf16* A = Ag + (long)bz * sAb + m0 * lda;
  const bf16* Bp = Bg + (long)bz * sBb + n0 * ldb;

  int w = t >> 6, l = t & 63;
  int lr = l >> 2;
  int lc = (((l & 3) ^ (lr & 3)) * 8);  // swizzled source chunk
  int quad = l >> 4, ln = l & 15;
  int wm = w >> 1, wn = w & 1;
  int rdoff = ((quad ^ (ln & 3)) * 8);  // swizzled read offset

  int Keff = (MODE == 2) ? (by + 1) * 128 : K;

  f32x4 acc[4][4];
#pragma unroll
  for (int i = 0; i < 4; i++)
#pragma unroll
    for (int j = 0; j < 4; j++) acc[i][j] = f32x4{0.f, 0.f, 0.f, 0.f};

  const bf16* a_base = As + (wm * 64 + ln) * 32 + rdoff;
  const bf16* b_base = Bs + (wn * 64 + ln) * 32 + rdoff;
  long arow0 = (long)(w * 16 + lr);

  for (int k0 = 0; k0 < Keff; k0 += 64) {
#pragma unroll
    for (int kk = 0; kk < 2; kk++) {
      int kc = k0 + kk * 32 + lc;
      gload_lds16(A + arow0 * lda + kc, As + kk * 4096 + w * 512);
      gload_lds16(A + (arow0 + 64) * lda + kc, As + kk * 4096 + 2048 + w * 512);
      gload_lds16(Bp + arow0 * ldb + kc, Bs + kk * 4096 + w * 512);
      gload_lds16(Bp + (arow0 + 64) * ldb + kc, Bs + kk * 4096 + 2048 + w * 512);
    }
    asm volatile("s_waitcnt vmcnt(0)" ::: "memory");
    __syncthreads();

#pragma unroll
    for (int kk = 0; kk < 2; kk++) {
      bf16x8 af[4], bfr[4];
#pragma unroll
      for (int i = 0; i < 4; i++) {
        af[i] = *(const bf16x8*)(a_base + kk * 4096 + i * 512);
        bfr[i] = *(const bf16x8*)(b_base + kk * 4096 + i * 512);
      }
#pragma unroll
      for (int i = 0; i < 4; i++)
#pragma unroll
        for (int j = 0; j < 4; j++)
          acc[i][j] = __builtin_amdgcn_mfma_f32_16x16x32_bf16(
              af[i], bfr[j], acc[i][j], 0, 0, 0);
    }
    __syncthreads();
  }

  // ---- epilogues: within each 16x16 tile, row = quad*4 + r, col = ln ----
  bool transposed = (MODE == 3) || (MODE == 4 && n0 >= 1024);
  if ((MODE == 0 || MODE == 4) && !transposed) {
    bf16* C = (bf16*)Cg + (long)bz * sCb + m0 * ldc + n0;
    const float* bptr = (MODE == 4) ? nullptr : bias;
#pragma unroll
    for (int i = 0; i < 4; i++) {
      int rb = wm * 64 + i * 16 + quad * 4;
#pragma unroll
      for (int j = 0; j < 4; j++) {
        int col = wn * 64 + j * 16 + ln;
        float bv_ = bptr ? bptr[n0 + col] : 0.f;
#pragma unroll
        for (int r = 0; r < 4; r++)
          C[(long)(rb + r) * ldc + col] = (bf16)(acc[i][j][r] + bv_);
      }
    }
  } else if (transposed) {
    // bounce through LDS, write transposed.
    bf16* tb;
    long tld;
    int d0i, s0i;
    const float* bptr;
    if (MODE == 4) {
      tb = vTp + (m0 >> 11) * (long)DD * SS;
      tld = SS;
      d0i = (int)n0 - 1024;
      s0i = (int)(m0 & 2047);
      bptr = bias;  // bv
    } else {
      tb = (bf16*)Cg;
      tld = ldc;
      d0i = (int)n0;
      s0i = (int)m0;
      bptr = nullptr;
    }
#pragma unroll
    for (int i = 0; i < 4; i++) {
      int sb = wm * 64 + i * 16 + quad * 4;
#pragma unroll
      for (int j = 0; j < 4; j++) {
        int d = wn * 64 + j * 16 + ln;
        float bv_ = bptr ? bptr[d0i + d] : 0.f;
#pragma unroll
        for (int r = 0; r < 4; r++)
          smem[d * 128 + ((sb + r) ^ (ln << 3))] = (bf16)(acc[i][j][r] + bv_);
      }
    }
    __syncthreads();
    int d = t >> 1, h = t & 1;
    bf16* dst = tb + (long)(d0i + d) * tld + s0i + h * 64;
#pragma unroll
    for (int j = 0; j < 8; j++) {
      int sbase = h * 64 + j * 8;
      bf16x8 v = *(const bf16x8*)(smem + d * 128 + (sbase ^ ((d & 15) << 3)));
      *(bf16x8*)(dst + j * 8) = v;
    }
  } else if (MODE == 1) {
    // fused-exp epilogue: p~ = exp((acc + beta[col])*scale), 0 above diag.
    const float* betap = bias + (long)bz * SS + n0;
#pragma unroll
    for (int i = 0; i < 4; i++) {
      int rb = wm * 64 + i * 16 + quad * 4;
#pragma unroll
      for (int j = 0; j < 4; j++) {
        int col = wn * 64 + j * 16 + ln;
        float bcol = betap[col];
#pragma unroll
        for (int r = 0; r < 4; r++) {
          int row = rb + r;
          float p = 0.f;
          if (n0 + col <= m0 + row)
            p = __expf((acc[i][j][r] + bcol) * scale);
          smem[row * 128 + (col ^ ((row & 15) << 3))] = (bf16)p;
        }
      }
    }
    __syncthreads();
    int row = t >> 1, h = t & 1;
    bf16* P = (bf16*)Cg + (long)bz * sCb + (m0 + row) * ldc + n0;
    float rsum = 0.f;
#pragma unroll
    for (int jj = 0; jj < 8; jj++) {
      int p8 = h * 8 + jj;  // 16B chunk index within 128 cols
      int slot = p8 ^ (row & 15);
      bf16x8 v = *(const bf16x8*)(smem + row * 128 + slot * 8);
#pragma unroll
      for (int e = 0; e < 8; e++) rsum += (float)v[e];
      *(bf16x8*)(P + p8 * 8) = v;
    }
    atomicAdd(&rowsums[(long)bz * SS + m0 + row], rsum);
  } else {
    // MODE 2: out = (P~ @ V) / rowsum
    float* C = (float*)Cg + (long)bz * sCb + m0 * ldc + n0;
    const float* rs = rowsums + (long)bz * SS + m0;
#pragma unroll
    for (int i = 0; i < 4; i++) {
      int rb = wm * 64 + i * 16 + quad * 4;
      float inv[4];
#pragma unroll
      for (int r = 0; r < 4; r++) inv[r] = 1.f / rs[rb + r];
#pragma unroll
      for (int j = 0; j < 4; j++) {
        int col = wn * 64 + j * 16 + ln;
#pragma unroll
        for (int r = 0; r < 4; r++)
          C[(long)(rb + r) * ldc + col] = acc[i][j][r] * inv[r];
      }
    }
  }
}

extern "C" void kernel_launch(void* const* d_in, const int* in_sizes, int n_in,
                              void* d_out, int out_size, void* d_ws,
                              size_t ws_size, hipStream_t stream) {
  const float* x = (const float*)d_in[0];
  const float* R = (const float*)d_in[1];
  const float* E = (const float*)d_in[2];
  const float* Wq = (const float*)d_in[3];
  const float* bq = (const float*)d_in[4];
  const float* Wk = (const float*)d_in[5];
  // const float* bk = (const float*)d_in[6];   // softmax-invariant: dropped
  const float* Wv = (const float*)d_in[7];
  const float* bv = (const float*)d_in[8];
  float* out = (float*)d_out;

  // Algebra: q = x*A + a, k = x*B + b with A = Wq^T R^T, a = R bq,
  //          B = Wk^T E^T, b = E bk.  S = q k^T = x M x^T + row-term (drop,
  //          softmax-invariant) + (x v)^T per column + const (drop), where
  //          M^T = Wk^T E^T R Wq = H Wq,  H = Wk^T G',  G' = E^T R,
  //          v = H bq,  beta = x v.
  char* ws = (char*)d_ws;
  bf16* xb = (bf16*)ws;                        // 16 MiB
  bf16* Tbuf = (bf16*)(ws + 16777216);         // 16 MiB (T = x M)
  bf16* vT = (bf16*)(ws + 33554432);           // 16 MiB
  bf16* probs = (bf16*)(ws + 50331648);        // 32 MiB
  bf16* RT = (bf16*)(ws + 83886080);           // 2 MiB
  bf16* ET = (bf16*)(ws + 85983232);           // 2 MiB
  bf16* WqT = (bf16*)(ws + 88080384);          // 2 MiB
  bf16* WkT = (bf16*)(ws + 90177536);          // 2 MiB
  bf16* GpT = (bf16*)(ws + 92274688);          // 2 MiB (G'^T)
  bf16* Hb = (bf16*)(ws + 94371840);           // 2 MiB (H)
  bf16* wcat = (bf16*)(ws + 96468992);         // 4 MiB ([M^T | Wv])
  float* rowsums = (float*)(ws + 100663296);   // 32 KiB
  float* beta = (float*)(ws + 100696064);      // 32 KiB
  float* vvec = (float*)(ws + 100728832);      // 4 KiB

  // 1) prep: cvt x, cvt Wv, transpose R/E/Wq/Wk, zero rowsums
  prep_all<<<13344, 256, 0, stream>>>(x, R, E, Wq, Wk, Wv, xb, RT, ET, WqT,
                                      WkT, wcat, rowsums);

  // 2) fold chain (each 1024^3):
  //    G'^T : G' = E^T R, written transposed
  gemm_bt<3><<<dim3(8, 8, 1), 256, 0, stream>>>(
      ET, DD, 0, RT, DD, 0, GpT, DD, 0, nullptr, 1.f, DD, nullptr, nullptr,
      nullptr, nullptr, nullptr, -1);
  //    H = Wk^T G' = WkT . (G'^T)^T
  gemm_bt<0><<<dim3(8, 8, 1), 256, 0, stream>>>(
      WkT, DD, 0, GpT, DD, 0, Hb, DD, 0, nullptr, 1.f, DD, nullptr, nullptr,
      nullptr, nullptr, nullptr, -1);
  //    M^T = H Wq = H . WqT^T  (+ GEMV blocks: v = H bq)
  gemm_bt<0><<<dim3(9, 8, 1), 256, 0, stream>>>(
      Hb, DD, 0, WqT, DD, 0, wcat, DD, 0, nullptr, 1.f, DD, nullptr, nullptr,
      Hb, bq, vvec, 8);

  // 3) fused T|V GEMM (M=8192, N=2048, K=1024): T = x.(M^T)^T -> Tbuf;
  //    V tiles (bx>=8) written transposed to vT with bias bv;
  //    bx==16 blocks: beta = xb . vvec
  gemm_bt<4><<<dim3(17, 64, 1), 256, 0, stream>>>(
      xb, DD, 0, wcat, DD, 0, Tbuf, DD, 0, bv, 1.f, DD, vT, nullptr, xb, vvec,
      beta, 16);

  // 4) causal scores S = (T x^T + beta)/32, fused exp -> bf16 probs + rowsums
  gemm_bt<1><<<dim3(136, 1, BB), 256, 0, stream>>>(
      Tbuf, DD, (long)SS * DD, xb, DD, (long)SS * DD, probs, SS, (long)SS * SS,
      beta, 0.03125f, DD, nullptr, rowsums, nullptr, nullptr, nullptr, -1);

  // 5) out = (P~ @ V) / rowsum : K truncated causally, long strips first
  gemm_bt<2><<<dim3(8, 16, BB), 256, 0, stream>>>(
      probs, SS, (long)SS * SS, vT, SS, (long)DD * SS, out, DD, (long)SS * DD,
      nullptr, 1.f, SS, nullptr, rowsums, nullptr, nullptr, nullptr, -1);
}

// Round 8
// 319.881 us; speedup vs baseline: 1.0536x; 1.0536x over previous
//
#include <hip/hip_runtime.h>
#include <hip/hip_bf16.h>
#include <stdint.h>
#include <math.h>

// Problem constants
#define DD 1024
#define SS 2048
#define BB 4

typedef __bf16 bf16;
typedef __bf16 bf16x8 __attribute__((ext_vector_type(8)));
typedef __bf16 bf16x4 __attribute__((ext_vector_type(4)));
typedef float f32x4 __attribute__((ext_vector_type(4)));
typedef float f32x16 __attribute__((ext_vector_type(16)));

// ---- async global->LDS 16B copy (dest = wave-uniform base + lane*16) ----
__device__ __forceinline__ void gload_lds16(const bf16* g, bf16* l) {
  __builtin_amdgcn_global_load_lds(
      (const __attribute__((address_space(1))) void*)g,
      (__attribute__((address_space(3))) void*)l, 16, 0, 0);
}

// ---- ALL preprocessing in ONE dispatch --------------------------------
// blocks [0,11264):     fp32->bf16 cvt of x, R, E, Wv
// blocks [11264,13312): transpose+cvt Wq -> WqT, Wk -> WkT
// blocks [13312,16384): bias fold (R@bq | E@bk | bv)
// blocks [16384,16416): zero rowsums (8192 floats)
__global__ __launch_bounds__(256) void prep_all(
    const float* __restrict__ x, const float* __restrict__ R,
    const float* __restrict__ E, const float* __restrict__ Wv,
    const float* __restrict__ Wq, const float* __restrict__ Wk,
    const float* __restrict__ bq, const float* __restrict__ bk,
    const float* __restrict__ bv, bf16* __restrict__ xb,
    bf16* __restrict__ Rb, bf16* __restrict__ Eb, bf16* __restrict__ Wvb,
    bf16* __restrict__ WqT, bf16* __restrict__ WkT, float* __restrict__ bias,
    float* __restrict__ rowsums) {
  int bid = blockIdx.x;
  int t = threadIdx.x;
  if (bid < 11264) {
    const float* src;
    bf16* dst;
    int base;
    if (bid < 8192) { src = x; dst = xb; base = bid; }
    else if (bid < 9216) { src = R; dst = Rb; base = bid - 8192; }
    else if (bid < 10240) { src = E; dst = Eb; base = bid - 9216; }
    else { src = Wv; dst = Wvb; base = bid - 10240; }
    int i = (base * 256 + t) * 4;
    float4 v = *(const float4*)(src + i);
    bf16x4 o;
    o.x = (bf16)v.x; o.y = (bf16)v.y; o.z = (bf16)v.z; o.w = (bf16)v.w;
    *(bf16x4*)(dst + i) = o;
  } else if (bid < 13312) {
    int r2 = bid - 11264;
    const float* src = (r2 >= 1024) ? Wk : Wq;
    bf16* dst = (r2 >= 1024) ? WkT : WqT;
    int rem = r2 & 1023;
    int bx = rem & 31, by = rem >> 5;
    __shared__ float tile[32][33];
    int tx = t & 31, ty = t >> 5;
    int xcol = bx * 32 + tx;
    int y0 = by * 32;
    for (int r = ty; r < 32; r += 8)
      tile[r][tx] = src[(y0 + r) * DD + xcol];
    __syncthreads();
    int dx = by * 32 + tx;
    int dy0 = bx * 32;
    for (int r = ty; r < 32; r += 8)
      dst[(dy0 + r) * DD + dx] = (bf16)tile[tx][r];
  } else if (bid < 16384) {
    int e = bid - 13312;  // 0..3071
    if (e >= 2048) { if (t == 0) bias[e] = bv[e - 2048]; return; }
    const float* M = (e < 1024) ? R : E;
    const float* bb = (e < 1024) ? bq : bk;
    int row = e & 1023;
    float s = 0.f;
    for (int f = t; f < DD; f += 256) s += M[row * DD + f] * bb[f];
    for (int o = 32; o >= 1; o >>= 1) s += __shfl_xor(s, o, 64);
    __shared__ float red[4];
    if ((t & 63) == 0) red[t >> 6] = s;
    __syncthreads();
    if (t == 0) bias[e] = red[0] + red[1] + red[2] + red[3];
  } else {
    int idx = (bid - 16384) * 256 + t;  // 0..8191
    rowsums[idx] = 0.f;
  }
}

// ---- bf16 GEMM: C = scale*(A @ B^T)(+bias), 128x128 tile, BK=64 --------
// Inner MFMA: 32x32x16 (2x2 blocks per 64x64 wave tile) — higher FLOP/cyc
// than 16x16x32 at identical LDS traffic. A/B frag: m=l&31, k=8*(l>>5)+j.
// C/D frag: col=l&31, row=(rr&3)+8*(rr>>2)+4*(l>>5)   [m74/m101 verified]
// MODE 0: C bf16 (+bias). If vTp set and n0>=2048 (QKV V-region), the tile
//         is written TRANSPOSED to vT[b][d][s] via swizzled LDS bounce.
// MODE 1: causal scores, fused exp: triangular blockIdx.x decode; p~ =
//         exp(scale*acc) (0 above diag) -> bf16 via LDS bounce; row sums
//         atomically added to rowsums[bz*SS+row].
// MODE 2: P~ @ V, K truncated at (by+1)*128, by reversed; out fp32/rowsum.
template <int MODE>
__global__ __launch_bounds__(256, 4)
void gemm_bt(const bf16* __restrict__ Ag, long lda, long sAb,
             const bf16* __restrict__ Bg, long ldb, long sBb,
             void* __restrict__ Cg, long ldc, long sCb,
             const float* __restrict__ bias, float scale, int K,
             bf16* __restrict__ vTp, float* __restrict__ rowsums) {
  __shared__ __align__(16) bf16 smem[16384];  // As | Bs ; reused for bounce
  bf16* As = smem;
  bf16* Bs = smem + 8192;

  int bx = blockIdx.x, by = blockIdx.y, bz = blockIdx.z;
  if (MODE == 1) {  // triangular decode: q -> (by, bx<=by)
    int q = bx;
    by = (int)((sqrtf(8.f * q + 1.f) - 1.f) * 0.5f);
    while ((by + 1) * (by + 2) / 2 <= q) by++;
    while (by * (by + 1) / 2 > q) by--;
    bx = q - by * (by + 1) / 2;
  }
  if (MODE == 2) by = 15 - by;  // longest K strips dispatch first
  long m0 = (long)by * 128, n0 = (long)bx * 128;
  const bf16* A = Ag + (long)bz * sAb + m0 * lda;
  const bf16* Bp = Bg + (long)bz * sBb + n0 * ldb;

  int t = threadIdx.x;
  int w = t >> 6, l = t & 63;
  int lr = l >> 2;
  int lc = (((l & 3) ^ (lr & 3)) * 8);  // swizzled staging source chunk
  int rl = l & 31, kh = l >> 5;         // MFMA lane decode (32x32)
  int wm = w >> 1, wn = w & 1;

  int Keff = (MODE == 2) ? (by + 1) * 128 : K;

  f32x16 acc[2][2];
#pragma unroll
  for (int g = 0; g < 2; g++)
#pragma unroll
    for (int h = 0; h < 2; h++)
#pragma unroll
      for (int rr = 0; rr < 16; rr++) acc[g][h][rr] = 0.f;

  const bf16* a_base = As + (wm * 64 + rl) * 32;
  const bf16* b_base = Bs + (wn * 64 + rl) * 32;
  long arow0 = (long)(w * 16 + lr);

  for (int k0 = 0; k0 < Keff; k0 += 64) {
#pragma unroll
    for (int kk = 0; kk < 2; kk++) {
      int kc = k0 + kk * 32 + lc;
      gload_lds16(A + arow0 * lda + kc, As + kk * 4096 + w * 512);
      gload_lds16(A + (arow0 + 64) * lda + kc, As + kk * 4096 + 2048 + w * 512);
      gload_lds16(Bp + arow0 * ldb + kc, Bs + kk * 4096 + w * 512);
      gload_lds16(Bp + (arow0 + 64) * ldb + kc, Bs + kk * 4096 + 2048 + w * 512);
    }
    asm volatile("s_waitcnt vmcnt(0)" ::: "memory");
    __syncthreads();

#pragma unroll
    for (int kk = 0; kk < 2; kk++) {
#pragma unroll
      for (int ks = 0; ks < 2; ks++) {
        int pos = ((ks * 2 + kh) ^ (rl & 3)) * 8;
        bf16x8 af[2], bfr[2];
#pragma unroll
        for (int g = 0; g < 2; g++)
          af[g] = *(const bf16x8*)(a_base + kk * 4096 + g * 1024 + pos);
#pragma unroll
        for (int h = 0; h < 2; h++)
          bfr[h] = *(const bf16x8*)(b_base + kk * 4096 + h * 1024 + pos);
#pragma unroll
        for (int g = 0; g < 2; g++)
#pragma unroll
          for (int h = 0; h < 2; h++)
            acc[g][h] = __builtin_amdgcn_mfma_f32_32x32x16_bf16(
                af[g], bfr[h], acc[g][h], 0, 0, 0);
      }
    }
    __syncthreads();
  }

  // ---- epilogues: C/D map col=rl, row=(rr&3)+8*(rr>>2)+4*kh ------------
  if (MODE == 0) {
    if (vTp && n0 >= 2048) {
      // V-region: bounce through LDS, write transposed to vT[b][d][s].
      int d0 = (int)n0 - 2048;
      int b = (int)(m0 >> 11);
      int s0 = (int)(m0 & 2047);
#pragma unroll
      for (int g = 0; g < 2; g++)
#pragma unroll
        for (int h = 0; h < 2; h++) {
          int d = wn * 64 + h * 32 + rl;
          float bv_ = bias[n0 + d];
#pragma unroll
          for (int rr = 0; rr < 16; rr++) {
            int s = wm * 64 + g * 32 + (rr & 3) + 8 * (rr >> 2) + 4 * kh;
            smem[d * 128 + (s ^ ((d & 15) << 3))] = (bf16)(acc[g][h][rr] + bv_);
          }
        }
      __syncthreads();
      int d = t >> 1, h = t & 1;
      bf16* dst = vTp + (long)b * DD * SS + (long)(d0 + d) * SS + s0 + h * 64;
#pragma unroll
      for (int j = 0; j < 8; j++) {
        int sbase = h * 64 + j * 8;
        bf16x8 v = *(const bf16x8*)(smem + d * 128 + (sbase ^ ((d & 15) << 3)));
        *(bf16x8*)(dst + j * 8) = v;
      }
    } else {
      bf16* C = (bf16*)Cg + (long)bz * sCb + m0 * ldc + n0;
#pragma unroll
      for (int g = 0; g < 2; g++)
#pragma unroll
        for (int h = 0; h < 2; h++) {
          int col = wn * 64 + h * 32 + rl;
          float bv_ = bias ? bias[n0 + col] : 0.f;
#pragma unroll
          for (int rr = 0; rr < 16; rr++) {
            int row = wm * 64 + g * 32 + (rr & 3) + 8 * (rr >> 2) + 4 * kh;
            C[(long)row * ldc + col] = (bf16)(acc[g][h][rr] + bv_);
          }
        }
    }
  } else if (MODE == 1) {
    // fused-exp epilogue: p~ = exp(scale*acc), 0 above diagonal.
#pragma unroll
    for (int g = 0; g < 2; g++)
#pragma unroll
      for (int h = 0; h < 2; h++) {
        int col = wn * 64 + h * 32 + rl;
#pragma unroll
        for (int rr = 0; rr < 16; rr++) {
          int row = wm * 64 + g * 32 + (rr & 3) + 8 * (rr >> 2) + 4 * kh;
          float p = 0.f;
          if (n0 + col <= m0 + row) p = __expf(acc[g][h][rr] * scale);
          smem[row * 128 + (col ^ ((row & 15) << 3))] = (bf16)p;
        }
      }
    __syncthreads();
    int row = t >> 1, h = t & 1;
    bf16* P = (bf16*)Cg + (long)bz * sCb + (m0 + row) * ldc + n0;
    float rsum = 0.f;
#pragma unroll
    for (int jj = 0; jj < 8; jj++) {
      int p8 = h * 8 + jj;  // 16B chunk index within 128 cols
      int slot = p8 ^ (row & 15);
      bf16x8 v = *(const bf16x8*)(smem + row * 128 + slot * 8);
#pragma unroll
      for (int e = 0; e < 8; e++) rsum += (float)v[e];
      *(bf16x8*)(P + p8 * 8) = v;
    }
    atomicAdd(&rowsums[(long)bz * SS + m0 + row], rsum);
  } else {
    // MODE 2: out = (P~ @ V) / rowsum
    float* C = (float*)Cg + (long)bz * sCb + m0 * ldc + n0;
    const float* rs = rowsums + (long)bz * SS + m0;
#pragma unroll
    for (int g = 0; g < 2; g++) {
      float inv[16];
#pragma unroll
      for (int rr = 0; rr < 16; rr++) {
        int row = wm * 64 + g * 32 + (rr & 3) + 8 * (rr >> 2) + 4 * kh;
        inv[rr] = 1.f / rs[row];
      }
#pragma unroll
      for (int h = 0; h < 2; h++) {
        int col = wn * 64 + h * 32 + rl;
#pragma unroll
        for (int rr = 0; rr < 16; rr++) {
          int row = wm * 64 + g * 32 + (rr & 3) + 8 * (rr >> 2) + 4 * kh;
          C[(long)row * ldc + col] = acc[g][h][rr] * inv[rr];
        }
      }
    }
  }
}

extern "C" void kernel_launch(void* const* d_in, const int* in_sizes, int n_in,
                              void* d_out, int out_size, void* d_ws,
                              size_t ws_size, hipStream_t stream) {
  const float* x = (const float*)d_in[0];
  const float* R = (const float*)d_in[1];
  const float* E = (const float*)d_in[2];
  const float* Wq = (const float*)d_in[3];
  const float* bq = (const float*)d_in[4];
  const float* Wk = (const float*)d_in[5];
  const float* bk = (const float*)d_in[6];
  const float* Wv = (const float*)d_in[7];
  const float* bv = (const float*)d_in[8];
  float* out = (float*)d_out;

  char* ws = (char*)d_ws;
  // Layout (128 MiB total, NO aliasing):
  //   qkv     @ 0       : 8192*3072 bf16 (V cols unused)  = 48 MiB
  //   vT      @ 48 MiB  : 4*1024*2048 bf16                = 16 MiB
  //   probs   @ 64 MiB  : 4*2048*2048 bf16 (unnormalized) = 32 MiB
  //   rowsums @ 96 MiB  : 8192 f32                        = 32 KiB
  //   prep    @ 97 MiB  : xb 16 | Rb 2 | Eb 2 | WqT 2 | WkT 2 | wcat 6 | bias
  bf16* qkv = (bf16*)ws;
  bf16* vT = (bf16*)(ws + 50331648);
  bf16* probs = (bf16*)(ws + 67108864);
  float* rowsums = (float*)(ws + 100663296);
  char* sr = ws + 101711872;
  bf16* xb = (bf16*)sr;                   // 16 MiB
  bf16* Rb = (bf16*)(sr + 16777216);      // 2 MiB
  bf16* Eb = Rb + 1024 * 1024;            // 2 MiB
  bf16* WqT = (bf16*)(sr + 20971520);     // 2 MiB
  bf16* WkT = WqT + 1024 * 1024;          // 2 MiB
  bf16* wcat = (bf16*)(sr + 25165824);    // 6 MiB (Wq'|Wk'|Wv)
  float* bias = (float*)(sr + 31457280);  // 12 KiB

  // 1) all preprocessing + rowsum zeroing: 1 dispatch
  prep_all<<<16416, 256, 0, stream>>>(x, R, E, Wv, Wq, Wk, bq, bk, bv, xb, Rb,
                                      Eb, wcat + 2048 * DD, WqT, WkT, bias,
                                      rowsums);

  // 2) fold weights (batched bz=2): Wq' = R@Wq ; Wk' = E@Wk
  gemm_bt<0><<<dim3(8, 8, 2), 256, 0, stream>>>(
      Rb, DD, 1024 * 1024, WqT, DD, 1024 * 1024, wcat, DD, 1024 * 1024,
      nullptr, 1.f, DD, nullptr, nullptr);

  // 3) fused QKV (M=8192, N=3072, K=1024); V-tiles written transposed to vT
  gemm_bt<0><<<dim3(24, 64, 1), 256, 0, stream>>>(xb, DD, 0, wcat, DD, 0, qkv,
                                                  3072, 0, bias, 1.f, DD, vT,
                                                  nullptr);

  // 4) causal scores + fused exp -> bf16 probs + row sums (136 tri tiles)
  gemm_bt<1><<<dim3(136, 1, BB), 256, 0, stream>>>(
      qkv, 3072, (long)SS * 3072, qkv + 1024, 3072, (long)SS * 3072, probs,
      SS, (long)SS * SS, nullptr, 0.03125f, DD, nullptr, rowsums);

  // 5) out = (P~ @ V) / rowsum : K truncated causally, long strips first
  gemm_bt<2><<<dim3(8, 16, BB), 256, 0, stream>>>(
      probs, SS, (long)SS * SS, vT, SS, (long)DD * SS, out, DD, (long)SS * DD,
      nullptr, 1.f, SS, nullptr, rowsums);
}